// Round 3
// baseline (44.786 us; speedup 1.0000x reference)
//
#include <hip/hip_runtime.h>

#define BATCH     4096
#define NCTX      8
#define NK        6
#define VDIM      256
#define NWORDS    50000
#define NPAIRS    (BATCH * NK)      // 24576
#define CBLK      32                // columns of O per block
#define MAXP      1024              // pair-list capacity (mean ~16, 1024 = impossible overflow)

// ---------------------------------------------------------------------------
// Kernel 1: x[b,:] = D[doc[b],:] + sum_c W[ctx[b,c],:]   -> d_ws (fp32, 4 MB)
// One wave per batch element, float4 per lane (fully coalesced).
// ---------------------------------------------------------------------------
__global__ __launch_bounds__(256)
void DM_42417097016803_xbuild(const int* __restrict__ ctx,
                              const int* __restrict__ doc,
                              const float* __restrict__ D,
                              const float* __restrict__ W,
                              float* __restrict__ x)
{
    const int wave = threadIdx.x >> 6;
    const int lane = threadIdx.x & 63;
    const int b    = blockIdx.x * 4 + wave;

    const float4* __restrict__ D4 = reinterpret_cast<const float4*>(D);
    const float4* __restrict__ W4 = reinterpret_cast<const float4*>(W);
    float4* __restrict__       x4 = reinterpret_cast<float4*>(x);

    const int docid = doc[b];
    float4 v = D4[(size_t)docid * 64 + lane];
#pragma unroll
    for (int c = 0; c < NCTX; ++c) {
        const int id = ctx[b * NCTX + c];
        const float4 w = W4[(size_t)id * 64 + lane];
        v.x += w.x; v.y += w.y; v.z += w.z; v.w += w.w;
    }
    x4[(size_t)b * 64 + lane] = v;
}

// ---------------------------------------------------------------------------
// Kernel 2: each block owns O columns [c0, c0+CBLK). Stream the 256 x CBLK
// tile into LDS (coalesced; O read exactly once chip-wide), scan the 24576
// target ids for matches, then one wave per matching (b,k) pair computes
// dot(x[b], O[:,id]) from the LDS tile.
// Tile layout [c][t] (+4 pad): pair-read is lane-contiguous ds_read_b128.
// ---------------------------------------------------------------------------
__global__ __launch_bounds__(256)
void DM_42417097016803_scoretile(const int* __restrict__ tgt,
                                 const float* __restrict__ x,
                                 const float* __restrict__ O,
                                 float* __restrict__ out)
{
    __shared__ float tile[CBLK][VDIM + 4];   // 32 x 260 floats = 33.3 KB
    __shared__ int   plist[MAXP];
    __shared__ int   pcount;

    const int tid = threadIdx.x;
    const int c0  = blockIdx.x * CBLK;
    const int ncols = (NWORDS - c0 < CBLK) ? (NWORDS - c0) : CBLK;

    if (tid == 0) pcount = 0;
    __syncthreads();

    // --- scan target ids (int4 loads; buffer is 98 KB, L2-resident) ---
    const int4* __restrict__ t4 = reinterpret_cast<const int4*>(tgt);
    for (int i = tid; i < NPAIRS / 4; i += 256) {
        const int4 v = t4[i];
        const int base = i * 4;
        if ((unsigned)(v.x - c0) < (unsigned)ncols) { int s = atomicAdd(&pcount, 1); if (s < MAXP) plist[s] = base + 0; }
        if ((unsigned)(v.y - c0) < (unsigned)ncols) { int s = atomicAdd(&pcount, 1); if (s < MAXP) plist[s] = base + 1; }
        if ((unsigned)(v.z - c0) < (unsigned)ncols) { int s = atomicAdd(&pcount, 1); if (s < MAXP) plist[s] = base + 2; }
        if ((unsigned)(v.w - c0) < (unsigned)ncols) { int s = atomicAdd(&pcount, 1); if (s < MAXP) plist[s] = base + 3; }
    }

    // --- load tile: 256 rows x CBLK cols; float4 per thread ---
    // thread -> (row group, float4 column): c4 = tid & 7, row = tid >> 3 (32 rows/iter)
    {
        const int c4  = tid & 7;        // 0..7 -> cols 4*c4 .. 4*c4+3
        const int row = tid >> 3;       // 0..31
#pragma unroll
        for (int rb = 0; rb < VDIM; rb += 32) {
            const int t = rb + row;
            if (c4 * 4 < ncols) {       // last block: ncols = 16 (mult of 4)
                const float4 v = *reinterpret_cast<const float4*>(
                    &O[(size_t)t * NWORDS + c0 + c4 * 4]);
                tile[c4 * 4 + 0][t] = v.x;
                tile[c4 * 4 + 1][t] = v.y;
                tile[c4 * 4 + 2][t] = v.z;
                tile[c4 * 4 + 3][t] = v.w;
            }
        }
    }
    __syncthreads();

    // --- one wave per matching pair ---
    const int wave = tid >> 6;
    const int lane = tid & 63;
    const int np   = (pcount < MAXP) ? pcount : MAXP;
    const float4* __restrict__ x4 = reinterpret_cast<const float4*>(x);

    for (int p = wave; p < np; p += 4) {
        const int i  = plist[p];
        const int c  = tgt[i] - c0;
        const int b  = i / NK;
        const float4 xv = x4[(size_t)b * 64 + lane];
        const float4 ov = *reinterpret_cast<const float4*>(&tile[c][lane * 4]);
        float d = xv.x * ov.x + xv.y * ov.y + xv.z * ov.z + xv.w * ov.w;
#pragma unroll
        for (int off = 32; off >= 1; off >>= 1)
            d += __shfl_down(d, off, 64);
        if (lane == 0) out[i] = d;
    }
}

// ---------------------------------------------------------------------------
// Fallback (direct strided-O gather) in case ws_size is too small for x.
// ---------------------------------------------------------------------------
__global__ __launch_bounds__(256)
void DM_42417097016803_fallback(const int* __restrict__ ctx,
                                const int* __restrict__ doc,
                                const int* __restrict__ tid,
                                const float* __restrict__ D,
                                const float* __restrict__ W,
                                const float* __restrict__ O,
                                float* __restrict__ out)
{
    const int b = blockIdx.x;
    const int t = threadIdx.x;

    __shared__ int s_idx[NCTX + NK + 1];
    if (t < NCTX)            s_idx[t] = ctx[b * NCTX + t];
    else if (t < NCTX + NK)  s_idx[t] = tid[b * NK + (t - NCTX)];
    else if (t == NCTX + NK) s_idx[t] = doc[b];
    __syncthreads();

    const int docid = s_idx[NCTX + NK];
    float x = D[(size_t)docid * VDIM + t];
#pragma unroll
    for (int c = 0; c < NCTX; ++c)
        x += W[(size_t)s_idx[c] * VDIM + t];

    float p[NK];
#pragma unroll
    for (int k = 0; k < NK; ++k)
        p[k] = x * O[(size_t)t * NWORDS + s_idx[NCTX + k]];

#pragma unroll
    for (int k = 0; k < NK; ++k) {
#pragma unroll
        for (int off = 32; off >= 1; off >>= 1)
            p[k] += __shfl_down(p[k], off, 64);
    }

    __shared__ float s_part[4][NK];
    const int wave = t >> 6;
    const int lane = t & 63;
    if (lane == 0) {
#pragma unroll
        for (int k = 0; k < NK; ++k) s_part[wave][k] = p[k];
    }
    __syncthreads();

    if (t < NK)
        out[b * NK + t] = s_part[0][t] + s_part[1][t] + s_part[2][t] + s_part[3][t];
}

extern "C" void kernel_launch(void* const* d_in, const int* in_sizes, int n_in,
                              void* d_out, int out_size, void* d_ws, size_t ws_size,
                              hipStream_t stream)
{
    const int*   ctx = (const int*)d_in[0];   // (4096, 8)
    const int*   doc = (const int*)d_in[1];   // (4096,)
    const int*   tid = (const int*)d_in[2];   // (4096, 6)
    const float* D   = (const float*)d_in[3]; // (100000, 256)
    const float* W   = (const float*)d_in[4]; // (50000, 256)
    const float* O   = (const float*)d_in[5]; // (256, 50000)
    float*       out = (float*)d_out;         // (4096, 6)

    const size_t x_bytes = (size_t)BATCH * VDIM * sizeof(float); // 4 MB

    if (ws_size >= x_bytes) {
        float* x = (float*)d_ws;
        DM_42417097016803_xbuild<<<BATCH / 4, 256, 0, stream>>>(ctx, doc, D, W, x);
        const int nblk = (NWORDS + CBLK - 1) / CBLK;  // 1563
        DM_42417097016803_scoretile<<<nblk, 256, 0, stream>>>(tid, x, O, out);
    } else {
        DM_42417097016803_fallback<<<BATCH, 256, 0, stream>>>(
            ctx, doc, tid, D, W, O, out);
    }
}

// Round 4
// 36.922 us; speedup vs baseline: 1.2130x; 1.2130x over previous
//
#include <hip/hip_runtime.h>

#define BATCH     4096
#define NCTX      8
#define NK        6
#define VDIM      256
#define NWORDS    50000
#define NPAIRS    (BATCH * NK)              // 24576
#define CBLK      32                        // columns of O per score block
#define NBINS     ((NWORDS + CBLK - 1) / CBLK)   // 1563
#define CAP       96                        // pairs per bin (mean 15.7; P(>=96) ~ 1e-40)

// ws layout: x (4 MB) | counts (NBINS ints) | bins (NBINS*CAP ints)
#define X_ELEMS   (BATCH * VDIM)

// ---------------------------------------------------------------------------
// Kernel 1: x[b,:] = D[doc[b],:] + sum_c W[ctx[b,c],:]  -> ws
// One wave per batch element, float4/lane. Block 0 also zeroes bin counters
// (visible to kernel 2 via stream ordering).
// ---------------------------------------------------------------------------
__global__ __launch_bounds__(256)
void DM_42417097016803_xbuild(const int* __restrict__ ctx,
                              const int* __restrict__ doc,
                              const float* __restrict__ D,
                              const float* __restrict__ W,
                              float* __restrict__ x,
                              int* __restrict__ counts)
{
    if (blockIdx.x == 0) {
        for (int j = threadIdx.x; j < NBINS; j += 256) counts[j] = 0;
    }

    const int wave = threadIdx.x >> 6;
    const int lane = threadIdx.x & 63;
    const int b    = blockIdx.x * 4 + wave;

    const float4* __restrict__ D4 = reinterpret_cast<const float4*>(D);
    const float4* __restrict__ W4 = reinterpret_cast<const float4*>(W);
    float4* __restrict__       x4 = reinterpret_cast<float4*>(x);

    const int docid = doc[b];
    float4 v = D4[(size_t)docid * 64 + lane];
#pragma unroll
    for (int c = 0; c < NCTX; ++c) {
        const int id = ctx[b * NCTX + c];
        const float4 w = W4[(size_t)id * 64 + lane];
        v.x += w.x; v.y += w.y; v.z += w.z; v.w += w.w;
    }
    x4[(size_t)b * 64 + lane] = v;
}

// ---------------------------------------------------------------------------
// Kernel 2: bin the 24576 (b,k) pairs by column-block of their target id.
// Stores packed (pair_idx << 5) | (col & 31).
// ---------------------------------------------------------------------------
__global__ __launch_bounds__(256)
void DM_42417097016803_bin(const int* __restrict__ tgt,
                           int* __restrict__ counts,
                           int* __restrict__ bins)
{
    const int i = blockIdx.x * 256 + threadIdx.x;   // exactly NPAIRS threads
    const int c = tgt[i];
    const int bin = c >> 5;                          // CBLK = 32
    const int pos = atomicAdd(&counts[bin], 1);
    if (pos < CAP) bins[bin * CAP + pos] = (i << 5) | (c & (CBLK - 1));
}

// ---------------------------------------------------------------------------
// Kernel 3: block bid owns O columns [bid*32, bid*32+32). Stream the 256x32
// tile into LDS (O read exactly once chip-wide, coalesced 128B/row), then one
// wave per binned pair computes dot(x[b], O[:,c]) from the LDS tile.
// Tile layout [c][t] stride 260: pair-read is contiguous ds_read_b128.
// ---------------------------------------------------------------------------
__global__ __launch_bounds__(256)
void DM_42417097016803_score(const int* __restrict__ counts,
                             const int* __restrict__ bins,
                             const float* __restrict__ x,
                             const float* __restrict__ O,
                             float* __restrict__ out)
{
    __shared__ float tile[CBLK][VDIM + 4];   // 33.3 KB

    const int tid = threadIdx.x;
    const int bid = blockIdx.x;
    const int c0  = bid * CBLK;
    const int ncols = (NWORDS - c0 < CBLK) ? (NWORDS - c0) : CBLK;

    // --- tile load: 8 float4-cols x 32 rows per iteration ---
    {
        const int c4  = tid & 7;        // float4 column within tile
        const int row = tid >> 3;       // 0..31
        if (c4 * 4 < ncols) {           // last block has ncols=16 (mult of 4)
#pragma unroll
            for (int rb = 0; rb < VDIM; rb += 32) {
                const int t = rb + row;
                const float4 v = *reinterpret_cast<const float4*>(
                    &O[(size_t)t * NWORDS + c0 + c4 * 4]);
                tile[c4 * 4 + 0][t] = v.x;
                tile[c4 * 4 + 1][t] = v.y;
                tile[c4 * 4 + 2][t] = v.z;
                tile[c4 * 4 + 3][t] = v.w;
            }
        }
    }

    int np = counts[bid];
    if (np > CAP) np = CAP;
    __syncthreads();

    // --- one wave per binned pair ---
    const int wave = tid >> 6;
    const int lane = tid & 63;
    const float4* __restrict__ x4 = reinterpret_cast<const float4*>(x);

    for (int p = wave; p < np; p += 4) {
        const int packed = bins[bid * CAP + p];
        const int i = packed >> 5;
        const int c = packed & (CBLK - 1);
        const int b = i / NK;
        const float4 xv = x4[(size_t)b * 64 + lane];
        const float4 ov = *reinterpret_cast<const float4*>(&tile[c][lane * 4]);
        float d = xv.x * ov.x + xv.y * ov.y + xv.z * ov.z + xv.w * ov.w;
#pragma unroll
        for (int off = 32; off >= 1; off >>= 1)
            d += __shfl_down(d, off, 64);
        if (lane == 0) out[i] = d;
    }
}

// ---------------------------------------------------------------------------
// Fallback (direct strided-O gather) in case ws is too small.
// ---------------------------------------------------------------------------
__global__ __launch_bounds__(256)
void DM_42417097016803_fallback(const int* __restrict__ ctx,
                                const int* __restrict__ doc,
                                const int* __restrict__ tid,
                                const float* __restrict__ D,
                                const float* __restrict__ W,
                                const float* __restrict__ O,
                                float* __restrict__ out)
{
    const int b = blockIdx.x;
    const int t = threadIdx.x;

    __shared__ int s_idx[NCTX + NK + 1];
    if (t < NCTX)            s_idx[t] = ctx[b * NCTX + t];
    else if (t < NCTX + NK)  s_idx[t] = tid[b * NK + (t - NCTX)];
    else if (t == NCTX + NK) s_idx[t] = doc[b];
    __syncthreads();

    const int docid = s_idx[NCTX + NK];
    float x = D[(size_t)docid * VDIM + t];
#pragma unroll
    for (int c = 0; c < NCTX; ++c)
        x += W[(size_t)s_idx[c] * VDIM + t];

    float p[NK];
#pragma unroll
    for (int k = 0; k < NK; ++k)
        p[k] = x * O[(size_t)t * NWORDS + s_idx[NCTX + k]];

#pragma unroll
    for (int k = 0; k < NK; ++k) {
#pragma unroll
        for (int off = 32; off >= 1; off >>= 1)
            p[k] += __shfl_down(p[k], off, 64);
    }

    __shared__ float s_part[4][NK];
    const int wave = t >> 6;
    const int lane = t & 63;
    if (lane == 0) {
#pragma unroll
        for (int k = 0; k < NK; ++k) s_part[wave][k] = p[k];
    }
    __syncthreads();

    if (t < NK)
        out[b * NK + t] = s_part[0][t] + s_part[1][t] + s_part[2][t] + s_part[3][t];
}

extern "C" void kernel_launch(void* const* d_in, const int* in_sizes, int n_in,
                              void* d_out, int out_size, void* d_ws, size_t ws_size,
                              hipStream_t stream)
{
    const int*   ctx = (const int*)d_in[0];   // (4096, 8)
    const int*   doc = (const int*)d_in[1];   // (4096,)
    const int*   tid = (const int*)d_in[2];   // (4096, 6)
    const float* D   = (const float*)d_in[3]; // (100000, 256)
    const float* W   = (const float*)d_in[4]; // (50000, 256)
    const float* O   = (const float*)d_in[5]; // (256, 50000)
    float*       out = (float*)d_out;         // (4096, 6)

    const size_t x_bytes     = (size_t)X_ELEMS * sizeof(float);       // 4 MB
    const size_t count_bytes = (size_t)NBINS * sizeof(int);
    const size_t bin_bytes   = (size_t)NBINS * CAP * sizeof(int);

    if (ws_size >= x_bytes + count_bytes + bin_bytes) {
        float* x      = (float*)d_ws;
        int*   counts = (int*)((char*)d_ws + x_bytes);
        int*   bins   = counts + NBINS;

        DM_42417097016803_xbuild<<<BATCH / 4, 256, 0, stream>>>(
            ctx, doc, D, W, x, counts);
        DM_42417097016803_bin<<<NPAIRS / 256, 256, 0, stream>>>(
            tid, counts, bins);
        DM_42417097016803_score<<<NBINS, 256, 0, stream>>>(
            counts, bins, x, O, out);
    } else {
        DM_42417097016803_fallback<<<BATCH, 256, 0, stream>>>(
            ctx, doc, tid, D, W, O, out);
    }
}